// Round 1
// baseline (234.809 us; speedup 1.0000x reference)
//
#include <hip/hip_runtime.h>

#define BB 8
#define LL 2048
#define DD 256

typedef _Float16 half8 __attribute__((ext_vector_type(8)));
typedef float floatx4 __attribute__((ext_vector_type(4)));
typedef unsigned short ushort8 __attribute__((ext_vector_type(8)));
typedef unsigned short ushort4v __attribute__((ext_vector_type(4)));

__device__ inline unsigned short f2h(float f) {
  _Float16 h = (_Float16)f;
  return __builtin_bit_cast(unsigned short, h);
}

// ---------------------------------------------------------------------------
// Kernel 1: QKV projection.  Out[r][o] = sum_h x[r][h] * W[o][h]  (nn.Linear)
// grid (256 row-tiles, 3 matrices), block 256.  fp32 in -> fp16 out (ws).
// ---------------------------------------------------------------------------
__global__ __launch_bounds__(256) void qkv_proj(
    const float* __restrict__ x,
    const float* __restrict__ Wq, const float* __restrict__ Wk,
    const float* __restrict__ Wv,
    unsigned short* __restrict__ Qb, unsigned short* __restrict__ Kb,
    unsigned short* __restrict__ Vb) {
  // stride 264: bank start = 4*m -> 2-way aliasing on ds_read_b128 (free)
  __shared__ __attribute__((aligned(16))) unsigned short Xs[64 * 264];
  __shared__ __attribute__((aligned(16))) unsigned short Ws[32 * 264];
  const int t = threadIdx.x;
  const int wave = t >> 6, lane = t & 63, quad = lane >> 4, m16 = lane & 15;
  const int r0 = blockIdx.x * 64;
  const float* W = (blockIdx.y == 0) ? Wq : (blockIdx.y == 1) ? Wk : Wv;
  unsigned short* Out = (blockIdx.y == 0) ? Qb : (blockIdx.y == 1) ? Kb : Vb;

  // stage x tile [64][256] -> fp16 LDS
  for (int p = 0; p < 16; ++p) {
    int idx = p * 1024 + t * 4;
    int row = idx >> 8, col = idx & 255;
    float4 v = *(const float4*)(x + (size_t)(r0 + row) * DD + col);
    ushort4v h = {f2h(v.x), f2h(v.y), f2h(v.z), f2h(v.w)};
    *(ushort4v*)&Xs[row * 264 + col] = h;
  }
  __syncthreads();

  // A-frags for this wave's 16 rows (A[m=lane&15][k=quad*8+j])
  half8 af[8];
  for (int kb = 0; kb < 8; ++kb)
    af[kb] = __builtin_bit_cast(
        half8, *(const ushort8*)&Xs[(wave * 16 + m16) * 264 + kb * 32 + quad * 8]);

  for (int c = 0; c < 8; ++c) {  // 8 col-tiles of 32 output features
    if (c) __syncthreads();
    for (int p = 0; p < 8; ++p) {
      int idx = p * 1024 + t * 4;
      int row = idx >> 8, col = idx & 255;
      float4 v = *(const float4*)(W + (size_t)(c * 32 + row) * DD + col);
      ushort4v h = {f2h(v.x), f2h(v.y), f2h(v.z), f2h(v.w)};
      *(ushort4v*)&Ws[row * 264 + col] = h;
    }
    __syncthreads();
    floatx4 acc[2] = {{0, 0, 0, 0}, {0, 0, 0, 0}};
    for (int n = 0; n < 2; ++n)
      for (int kb = 0; kb < 8; ++kb) {
        half8 bf = __builtin_bit_cast(
            half8,
            *(const ushort8*)&Ws[(n * 16 + m16) * 264 + kb * 32 + quad * 8]);
        acc[n] = __builtin_amdgcn_mfma_f32_16x16x32_f16(af[kb], bf, acc[n], 0, 0, 0);
      }
    // C/D layout: col = lane&15, row = quad*4 + reg
    for (int n = 0; n < 2; ++n)
      for (int r = 0; r < 4; ++r) {
        int rowg = r0 + wave * 16 + quad * 4 + r;
        int colg = c * 32 + n * 16 + m16;
        Out[(size_t)rowg * DD + colg] = f2h(acc[n][r]);
      }
  }
}

// ---------------------------------------------------------------------------
// Kernel 2: flash attention with key-padding mask.
// grid (32 q-tiles, 8 batches), block 256 (4 waves x 16 q-rows).
// KV-tile = 32.  K in LDS row-major, V in LDS transposed, P via LDS.
// ---------------------------------------------------------------------------
__global__ __launch_bounds__(256) void attn(
    const unsigned short* __restrict__ Qb, const unsigned short* __restrict__ Kb,
    const unsigned short* __restrict__ Vb, const int* __restrict__ lens,
    float* __restrict__ out) {
  __shared__ __attribute__((aligned(16))) unsigned short Ks[32 * 264];
  __shared__ __attribute__((aligned(16))) unsigned short Vt[256 * 40];
  __shared__ __attribute__((aligned(16))) unsigned short Ps[4 * 16 * 40];
  const int t = threadIdx.x;
  const int wave = t >> 6, lane = t & 63, quad = lane >> 4, m16 = lane & 15;
  const int b = blockIdx.y;
  const int q0 = blockIdx.x * 64;
  const int len = lens[b];
  const size_t base = (size_t)b * LL * DD;

  // Q A-frags for this wave's 16 rows, all 8 k-blocks (K=256)
  half8 qf[8];
  {
    const size_t row = base + (size_t)(q0 + wave * 16 + m16) * DD;
    for (int kb = 0; kb < 8; ++kb)
      qf[kb] = __builtin_bit_cast(half8,
                                  *(const ushort8*)(Qb + row + kb * 32 + quad * 8));
  }
  floatx4 O[16];
  for (int i = 0; i < 16; ++i) O[i] = (floatx4){0, 0, 0, 0};
  float mrow[4] = {-1e30f, -1e30f, -1e30f, -1e30f};
  float lrow[4] = {0.f, 0.f, 0.f, 0.f};
  unsigned short* Pw = &Ps[wave * 16 * 40];

  for (int kv0 = 0; kv0 < len; kv0 += 32) {
    __syncthreads();  // previous iter's LDS reads done before restage
    // stage K tile [32][256]
    {
      int row = t >> 3, col0 = (t & 7) * 32;
      const unsigned short* src = Kb + base + (size_t)(kv0 + row) * DD + col0;
      unsigned short* dst = &Ks[row * 264 + col0];
      for (int j = 0; j < 4; ++j)
        *(ushort8*)(dst + j * 8) = *(const ushort8*)(src + j * 8);
    }
    // stage V tile transposed: Vt[d][l], d = t (coalesced global reads)
    {
      const unsigned short* src = Vb + base + (size_t)kv0 * DD + t;
      for (int j = 0; j < 4; ++j) {
        ushort8 v;
        for (int i = 0; i < 8; ++i) v[i] = src[(size_t)(j * 8 + i) * DD];
        *(ushort8*)&Vt[t * 40 + j * 8] = v;
      }
    }
    __syncthreads();

    // S = Q Kt : 2 n-blocks x 8 k-steps
    floatx4 s[2] = {{0, 0, 0, 0}, {0, 0, 0, 0}};
    for (int n = 0; n < 2; ++n)
      for (int kb = 0; kb < 8; ++kb) {
        half8 kf = __builtin_bit_cast(
            half8,
            *(const ushort8*)&Ks[(n * 16 + m16) * 264 + kb * 32 + quad * 8]);
        s[n] = __builtin_amdgcn_mfma_f32_16x16x32_f16(qf[kb], kf, s[n], 0, 0, 0);
      }
    // scale + key-padding mask (col = kv0 + n*16 + lane&15, same for all regs)
    float sv[2][4];
    for (int n = 0; n < 2; ++n) {
      bool valid = (kv0 + n * 16 + m16) < len;
      for (int r = 0; r < 4; ++r)
        sv[n][r] = valid ? s[n][r] * 0.0625f : -1e30f;
    }
    // online softmax: row max over 16 lanes of this quad-group
    float al[4];
    for (int r = 0; r < 4; ++r) {
      float v = fmaxf(sv[0][r], sv[1][r]);
      v = fmaxf(v, __shfl_xor(v, 1));
      v = fmaxf(v, __shfl_xor(v, 2));
      v = fmaxf(v, __shfl_xor(v, 4));
      v = fmaxf(v, __shfl_xor(v, 8));
      float mn = fmaxf(mrow[r], v);
      al[r] = __expf(mrow[r] - mn);
      mrow[r] = mn;
    }
    // P = exp(S - m); row sums; write P (C-layout) to LDS as fp16
    float rs[4];
    for (int r = 0; r < 4; ++r) {
      float p0 = __expf(sv[0][r] - mrow[r]);
      float p1 = __expf(sv[1][r] - mrow[r]);
      Pw[(quad * 4 + r) * 40 + m16] = f2h(p0);
      Pw[(quad * 4 + r) * 40 + 16 + m16] = f2h(p1);
      float sum = p0 + p1;
      sum += __shfl_xor(sum, 1);
      sum += __shfl_xor(sum, 2);
      sum += __shfl_xor(sum, 4);
      sum += __shfl_xor(sum, 8);
      rs[r] = sum;
    }
    for (int r = 0; r < 4; ++r) lrow[r] = lrow[r] * al[r] + rs[r];
    // rescale O
    for (int i = 0; i < 16; ++i)
      for (int r = 0; r < 4; ++r) O[i][r] *= al[r];
    // PV: read P back in A-layout (intra-wave LDS dependency, compiler waits)
    half8 pf = __builtin_bit_cast(half8,
                                  *(const ushort8*)&Pw[m16 * 40 + quad * 8]);
    for (int nb = 0; nb < 16; ++nb) {
      half8 vf = __builtin_bit_cast(
          half8, *(const ushort8*)&Vt[(nb * 16 + m16) * 40 + quad * 8]);
      O[nb] = __builtin_amdgcn_mfma_f32_16x16x32_f16(pf, vf, O[nb], 0, 0, 0);
    }
  }
  // epilogue: out = O / l  (fp32)
  for (int nb = 0; nb < 16; ++nb)
    for (int r = 0; r < 4; ++r) {
      int rowg = q0 + wave * 16 + quad * 4 + r;
      int colg = nb * 16 + m16;
      out[base + (size_t)rowg * DD + colg] = O[nb][r] / lrow[r];
    }
}

extern "C" void kernel_launch(void* const* d_in, const int* in_sizes, int n_in,
                              void* d_out, int out_size, void* d_ws, size_t ws_size,
                              hipStream_t stream) {
  const float* x = (const float*)d_in[0];
  const float* Wq = (const float*)d_in[1];
  const float* Wk = (const float*)d_in[2];
  const float* Wv = (const float*)d_in[3];
  const int* lens = (const int*)d_in[4];
  unsigned short* Qb = (unsigned short*)d_ws;
  unsigned short* Kb = Qb + (size_t)BB * LL * DD;
  unsigned short* Vb = Kb + (size_t)BB * LL * DD;
  float* out = (float*)d_out;

  qkv_proj<<<dim3(256, 3), 256, 0, stream>>>(x, Wq, Wk, Wv, Qb, Kb, Vb);
  attn<<<dim3(32, 8), 256, 0, stream>>>(Qb, Kb, Vb, lens, out);
}

// Round 2
// 218.157 us; speedup vs baseline: 1.0763x; 1.0763x over previous
//
#include <hip/hip_runtime.h>

#define BB 8
#define LL 2048
#define DD 256

typedef _Float16 half8 __attribute__((ext_vector_type(8)));
typedef float floatx4 __attribute__((ext_vector_type(4)));
typedef unsigned short ushort8 __attribute__((ext_vector_type(8)));
typedef unsigned short ushort4v __attribute__((ext_vector_type(4)));

__device__ inline unsigned short f2h(float f) {
  _Float16 h = (_Float16)f;
  return __builtin_bit_cast(unsigned short, h);
}

// ---------------------------------------------------------------------------
// Kernel 1: Q/K projection.  Out[r][o] = sum_h x[r][h] * W[o][h]
// grid (256 row-tiles, 2 matrices), block 256.  fp32 in -> fp16 [l][d] out.
// ---------------------------------------------------------------------------
__global__ __launch_bounds__(256) void qk_proj(
    const float* __restrict__ x,
    const float* __restrict__ Wq, const float* __restrict__ Wk,
    unsigned short* __restrict__ Qb, unsigned short* __restrict__ Kb) {
  __shared__ __attribute__((aligned(16))) unsigned short Xs[64 * 264];
  __shared__ __attribute__((aligned(16))) unsigned short Ws[32 * 264];
  const int t = threadIdx.x;
  const int wave = t >> 6, lane = t & 63, quad = lane >> 4, m16 = lane & 15;
  const int r0 = blockIdx.x * 64;
  const float* W = (blockIdx.y == 0) ? Wq : Wk;
  unsigned short* Out = (blockIdx.y == 0) ? Qb : Kb;

  for (int p = 0; p < 16; ++p) {
    int idx = p * 1024 + t * 4;
    int row = idx >> 8, col = idx & 255;
    float4 v = *(const float4*)(x + (size_t)(r0 + row) * DD + col);
    ushort4v h = {f2h(v.x), f2h(v.y), f2h(v.z), f2h(v.w)};
    *(ushort4v*)&Xs[row * 264 + col] = h;
  }
  __syncthreads();

  half8 af[8];
  for (int kb = 0; kb < 8; ++kb)
    af[kb] = __builtin_bit_cast(
        half8, *(const ushort8*)&Xs[(wave * 16 + m16) * 264 + kb * 32 + quad * 8]);

  for (int c = 0; c < 8; ++c) {
    if (c) __syncthreads();
    for (int p = 0; p < 8; ++p) {
      int idx = p * 1024 + t * 4;
      int row = idx >> 8, col = idx & 255;
      float4 v = *(const float4*)(W + (size_t)(c * 32 + row) * DD + col);
      ushort4v h = {f2h(v.x), f2h(v.y), f2h(v.z), f2h(v.w)};
      *(ushort4v*)&Ws[row * 264 + col] = h;
    }
    __syncthreads();
    floatx4 acc[2] = {{0, 0, 0, 0}, {0, 0, 0, 0}};
    for (int n = 0; n < 2; ++n)
      for (int kb = 0; kb < 8; ++kb) {
        half8 bf = __builtin_bit_cast(
            half8,
            *(const ushort8*)&Ws[(n * 16 + m16) * 264 + kb * 32 + quad * 8]);
        acc[n] = __builtin_amdgcn_mfma_f32_16x16x32_f16(af[kb], bf, acc[n], 0, 0, 0);
      }
    for (int n = 0; n < 2; ++n)
      for (int r = 0; r < 4; ++r) {
        int rowg = r0 + wave * 16 + quad * 4 + r;
        int colg = c * 32 + n * 16 + m16;
        Out[(size_t)rowg * DD + colg] = f2h(acc[n][r]);
      }
  }
}

// ---------------------------------------------------------------------------
// Kernel 1b: V projection writing V TRANSPOSED:  VT[b][d][l].
// Operand roles swapped (A = W so C-layout col=lane&15 lands on the L dim,
// making the fp16 stores coalesced along l).  grid 256, block 256.
// ---------------------------------------------------------------------------
__global__ __launch_bounds__(256) void vproj_t(
    const float* __restrict__ x, const float* __restrict__ Wv,
    unsigned short* __restrict__ VT) {
  __shared__ __attribute__((aligned(16))) unsigned short Xs[64 * 264];
  __shared__ __attribute__((aligned(16))) unsigned short Ws[64 * 264];
  const int t = threadIdx.x;
  const int wave = t >> 6, lane = t & 63, quad = lane >> 4, m16 = lane & 15;
  const int l0 = blockIdx.x * 64;          // global row block (never crosses batch)
  const int b = l0 >> 11, lb = l0 & 2047;

  for (int p = 0; p < 16; ++p) {
    int idx = p * 1024 + t * 4;
    int row = idx >> 8, col = idx & 255;
    float4 v = *(const float4*)(x + (size_t)(l0 + row) * DD + col);
    ushort4v h = {f2h(v.x), f2h(v.y), f2h(v.z), f2h(v.w)};
    *(ushort4v*)&Xs[row * 264 + col] = h;
  }
  __syncthreads();

  // B-frags from x: B[n=l][k=h], this wave owns l-subtile wave*16
  half8 xf[8];
  for (int kb = 0; kb < 8; ++kb)
    xf[kb] = __builtin_bit_cast(
        half8, *(const ushort8*)&Xs[(wave * 16 + m16) * 264 + kb * 32 + quad * 8]);

  for (int c = 0; c < 4; ++c) {   // 4 chunks of 64 output features (o)
    if (c) __syncthreads();
    for (int p = 0; p < 16; ++p) {
      int idx = p * 1024 + t * 4;
      int row = idx >> 8, col = idx & 255;
      float4 v = *(const float4*)(Wv + (size_t)(c * 64 + row) * DD + col);
      ushort4v h = {f2h(v.x), f2h(v.y), f2h(v.z), f2h(v.w)};
      *(ushort4v*)&Ws[row * 264 + col] = h;
    }
    __syncthreads();
    for (int mt = 0; mt < 4; ++mt) {
      floatx4 acc = {0, 0, 0, 0};
      for (int kb = 0; kb < 8; ++kb) {
        half8 af = __builtin_bit_cast(
            half8,
            *(const ushort8*)&Ws[(mt * 16 + m16) * 264 + kb * 32 + quad * 8]);
        acc = __builtin_amdgcn_mfma_f32_16x16x32_f16(af, xf[kb], acc, 0, 0, 0);
      }
      // D: row(m)=quad*4+r -> o ; col(n)=m16 -> l  => coalesced along l
      int o = c * 64 + mt * 16 + quad * 4;
      int l = lb + wave * 16 + m16;
      for (int r = 0; r < 4; ++r)
        VT[((size_t)(b * DD + o + r)) * LL + l] = f2h(acc[r]);
    }
  }
}

// ---------------------------------------------------------------------------
// Kernel 2: flash attention.  grid (32 q-tiles, 8 batches), block 256.
// KV-tile 64, register double-buffered staging, V already transposed.
// ---------------------------------------------------------------------------
__global__ __launch_bounds__(256, 1) void attn(
    const unsigned short* __restrict__ Qb, const unsigned short* __restrict__ Kb,
    const unsigned short* __restrict__ VT, const int* __restrict__ lens,
    float* __restrict__ out) {
  __shared__ __attribute__((aligned(16))) unsigned short Ks[64 * 264];
  __shared__ __attribute__((aligned(16))) unsigned short Vs[256 * 72];
  __shared__ __attribute__((aligned(16))) unsigned short Ps[4 * 16 * 72];
  const int t = threadIdx.x;
  const int wave = t >> 6, lane = t & 63, quad = lane >> 4, m16 = lane & 15;
  const int b = blockIdx.y;
  const int q0 = blockIdx.x * 64;
  const int len = lens[b];
  const size_t baseQK = (size_t)b * LL * DD;  // [l][d]
  const size_t baseVT = (size_t)b * DD * LL;  // [d][l]

  // Q A-frags for this wave's 16 q-rows
  half8 qf[8];
  {
    const unsigned short* qrow =
        Qb + baseQK + (size_t)(q0 + wave * 16 + m16) * DD + quad * 8;
    for (int kb = 0; kb < 8; ++kb)
      qf[kb] = __builtin_bit_cast(half8, *(const ushort8*)(qrow + kb * 32));
  }

  floatx4 O[16];
  for (int i = 0; i < 16; ++i) O[i] = (floatx4){0, 0, 0, 0};
  float mrow[4] = {-1e30f, -1e30f, -1e30f, -1e30f};
  float lrow[4] = {0.f, 0.f, 0.f, 0.f};
  unsigned short* Pw = &Ps[wave * 16 * 72];

  // register prefetch buffers: K 64x256 and VT 256x64, 8 b128 chunks each
  ushort8 kreg[8], vreg[8];
  const unsigned short* kbase = Kb + baseQK;
  const unsigned short* vbase = VT + baseVT;

#define LOAD_TILES(KV0)                                                   \
  {                                                                       \
    const unsigned short* kp = kbase + (size_t)(KV0)*DD;                  \
    for (int c = 0; c < 8; ++c)                                           \
      kreg[c] = *(const ushort8*)(kp + (t + c * 256) * 8);                \
    for (int c = 0; c < 8; ++c) {                                         \
      int chunk = t + c * 256;                                            \
      vreg[c] = *(const ushort8*)(vbase + (size_t)(chunk >> 3) * LL +     \
                                  (KV0) + (chunk & 7) * 8);               \
    }                                                                     \
  }

  LOAD_TILES(0);

  for (int kv0 = 0; kv0 < len; kv0 += 64) {
    __syncthreads();  // all waves done reading previous LDS tile
    for (int c = 0; c < 8; ++c) {
      int chunk = t + c * 256;
      *(ushort8*)&Ks[(chunk >> 5) * 264 + (chunk & 31) * 8] = kreg[c];
    }
    for (int c = 0; c < 8; ++c) {
      int chunk = t + c * 256;
      *(ushort8*)&Vs[(chunk >> 3) * 72 + (chunk & 7) * 8] = vreg[c];
    }
    __syncthreads();  // LDS ready
    if (kv0 + 64 < len) LOAD_TILES(kv0 + 64);  // overlap with compute below

    // S = Q K^T : 4 n-blocks x 8 k-steps
    floatx4 s[4];
    for (int n = 0; n < 4; ++n) s[n] = (floatx4){0, 0, 0, 0};
    for (int kb = 0; kb < 8; ++kb)
      for (int n = 0; n < 4; ++n) {
        half8 kf = __builtin_bit_cast(
            half8,
            *(const ushort8*)&Ks[(n * 16 + m16) * 264 + kb * 32 + quad * 8]);
        s[n] = __builtin_amdgcn_mfma_f32_16x16x32_f16(qf[kb], kf, s[n], 0, 0, 0);
      }
    // scale + key-padding mask (col = kv0 + n*16 + m16)
    float sv[4][4];
    for (int n = 0; n < 4; ++n) {
      bool valid = (kv0 + n * 16 + m16) < len;
      for (int r = 0; r < 4; ++r)
        sv[n][r] = valid ? s[n][r] * 0.0625f : -1e30f;
    }
    // online softmax per q-row (rows live on 16-lane m16 groups)
    float al[4];
    for (int r = 0; r < 4; ++r) {
      float v = fmaxf(fmaxf(sv[0][r], sv[1][r]), fmaxf(sv[2][r], sv[3][r]));
      v = fmaxf(v, __shfl_xor(v, 1));
      v = fmaxf(v, __shfl_xor(v, 2));
      v = fmaxf(v, __shfl_xor(v, 4));
      v = fmaxf(v, __shfl_xor(v, 8));
      float mn = fmaxf(mrow[r], v);
      al[r] = __expf(mrow[r] - mn);
      mrow[r] = mn;
      float sum = 0.f;
      for (int n = 0; n < 4; ++n) {
        float p = __expf(sv[n][r] - mn);
        Pw[(quad * 4 + r) * 72 + n * 16 + m16] = f2h(p);
        sum += p;
      }
      sum += __shfl_xor(sum, 1);
      sum += __shfl_xor(sum, 2);
      sum += __shfl_xor(sum, 4);
      sum += __shfl_xor(sum, 8);
      lrow[r] = lrow[r] * al[r] + sum;
    }
    for (int i = 0; i < 16; ++i)
      for (int r = 0; r < 4; ++r) O[i][r] *= al[r];
    // P back in A-layout (intra-wave LDS; compiler inserts lgkm waits)
    half8 pf0 = __builtin_bit_cast(half8,
                                   *(const ushort8*)&Pw[m16 * 72 + quad * 8]);
    half8 pf1 = __builtin_bit_cast(
        half8, *(const ushort8*)&Pw[m16 * 72 + 32 + quad * 8]);
    for (int nb = 0; nb < 16; ++nb) {
      half8 vf0 = __builtin_bit_cast(
          half8, *(const ushort8*)&Vs[(nb * 16 + m16) * 72 + quad * 8]);
      O[nb] = __builtin_amdgcn_mfma_f32_16x16x32_f16(pf0, vf0, O[nb], 0, 0, 0);
      half8 vf1 = __builtin_bit_cast(
          half8, *(const ushort8*)&Vs[(nb * 16 + m16) * 72 + 32 + quad * 8]);
      O[nb] = __builtin_amdgcn_mfma_f32_16x16x32_f16(pf1, vf1, O[nb], 0, 0, 0);
    }
  }
#undef LOAD_TILES

  for (int nb = 0; nb < 16; ++nb)
    for (int r = 0; r < 4; ++r) {
      int rowg = q0 + wave * 16 + quad * 4 + r;
      int colg = nb * 16 + m16;
      out[baseQK + (size_t)rowg * DD + colg] = O[nb][r] / lrow[r];
    }
}

extern "C" void kernel_launch(void* const* d_in, const int* in_sizes, int n_in,
                              void* d_out, int out_size, void* d_ws, size_t ws_size,
                              hipStream_t stream) {
  const float* x = (const float*)d_in[0];
  const float* Wq = (const float*)d_in[1];
  const float* Wk = (const float*)d_in[2];
  const float* Wv = (const float*)d_in[3];
  const int* lens = (const int*)d_in[4];
  unsigned short* Qb = (unsigned short*)d_ws;
  unsigned short* Kb = Qb + (size_t)BB * LL * DD;
  unsigned short* VT = Kb + (size_t)BB * LL * DD;
  float* out = (float*)d_out;

  qk_proj<<<dim3(256, 2), 256, 0, stream>>>(x, Wq, Wk, Qb, Kb);
  vproj_t<<<dim3(256), 256, 0, stream>>>(x, Wv, VT);
  attn<<<dim3(32, 8), 256, 0, stream>>>(Qb, Kb, VT, lens, out);
}

// Round 3
// 194.244 us; speedup vs baseline: 1.2088x; 1.1231x over previous
//
#include <hip/hip_runtime.h>

#define BB 8
#define LL 2048
#define DD 256

typedef _Float16 half8 __attribute__((ext_vector_type(8)));
typedef float floatx4 __attribute__((ext_vector_type(4)));
typedef unsigned short ushort8 __attribute__((ext_vector_type(8)));

__device__ inline unsigned short f2h(float f) {
  _Float16 h = (_Float16)f;
  return __builtin_bit_cast(unsigned short, h);
}

// ---------------------------------------------------------------------------
// Kernel 0: W fp32 -> fp16, Wh[3][256][256].  grid 96, block 256.
// ---------------------------------------------------------------------------
__global__ __launch_bounds__(256) void wcvt(
    const float* __restrict__ Wq, const float* __restrict__ Wk,
    const float* __restrict__ Wv, unsigned short* __restrict__ Wh) {
  const int bm = blockIdx.x >> 5;
  const float* src = (bm == 0) ? Wq : (bm == 1) ? Wk : Wv;
  const int off = (blockIdx.x & 31) * 2048 + threadIdx.x * 8;
  float4 a = *(const float4*)(src + off);
  float4 b = *(const float4*)(src + off + 4);
  ushort8 u = {f2h(a.x), f2h(a.y), f2h(a.z), f2h(a.w),
               f2h(b.x), f2h(b.y), f2h(b.z), f2h(b.w)};
  *(ushort8*)(Wh + bm * 65536 + off) = u;
}

// ---------------------------------------------------------------------------
// Kernel 1: fused QKV projection, no LDS, no barriers.
// grid 512 (32-row tiles), block 256 (4 waves).  Each wave: 12 of 48 n-tiles.
// Q,K stored [l][d]; V stored transposed VT[b][d][l] via operand swap.
// ---------------------------------------------------------------------------
__global__ __launch_bounds__(256) void proj(
    const float* __restrict__ x, const unsigned short* __restrict__ Wh,
    unsigned short* __restrict__ Qb, unsigned short* __restrict__ Kb,
    unsigned short* __restrict__ VT) {
  const int t = threadIdx.x;
  const int wave = t >> 6, lane = t & 63, quad = lane >> 4, m16 = lane & 15;
  const int l0g = blockIdx.x * 32;      // global row (16384 total)
  const int b = l0g >> 11, lb = l0g & 2047;

  // x A/B-frags for both 16-row subtiles, fp32 -> fp16 in-register
  half8 xf[2][8];
  for (int mt = 0; mt < 2; ++mt) {
    const float* xp = x + (size_t)(l0g + mt * 16 + m16) * DD + quad * 8;
    for (int kb = 0; kb < 8; ++kb) {
      float4 a = *(const float4*)(xp + kb * 32);
      float4 c = *(const float4*)(xp + kb * 32 + 4);
      ushort8 u = {f2h(a.x), f2h(a.y), f2h(a.z), f2h(a.w),
                   f2h(c.x), f2h(c.y), f2h(c.z), f2h(c.w)};
      xf[mt][kb] = __builtin_bit_cast(half8, u);
    }
  }

  for (int j = 0; j < 12; ++j) {
    const int nt = wave * 12 + j;
    const int mat = nt >> 4, ot = nt & 15;
    const unsigned short* wp =
        Wh + mat * 65536 + (ot * 16 + m16) * DD + quad * 8;
    floatx4 acc[2] = {{0, 0, 0, 0}, {0, 0, 0, 0}};
    if (mat < 2) {
      for (int kb = 0; kb < 8; ++kb) {
        half8 wf = __builtin_bit_cast(half8, *(const ushort8*)(wp + kb * 32));
        acc[0] = __builtin_amdgcn_mfma_f32_16x16x32_f16(xf[0][kb], wf, acc[0], 0, 0, 0);
        acc[1] = __builtin_amdgcn_mfma_f32_16x16x32_f16(xf[1][kb], wf, acc[1], 0, 0, 0);
      }
      unsigned short* Out = mat ? Kb : Qb;
      for (int mt = 0; mt < 2; ++mt)
        for (int r = 0; r < 4; ++r)
          Out[(size_t)(l0g + mt * 16 + quad * 4 + r) * DD + ot * 16 + m16] =
              f2h(acc[mt][r]);
    } else {
      for (int kb = 0; kb < 8; ++kb) {
        half8 wf = __builtin_bit_cast(half8, *(const ushort8*)(wp + kb * 32));
        acc[0] = __builtin_amdgcn_mfma_f32_16x16x32_f16(wf, xf[0][kb], acc[0], 0, 0, 0);
        acc[1] = __builtin_amdgcn_mfma_f32_16x16x32_f16(wf, xf[1][kb], acc[1], 0, 0, 0);
      }
      // D: row -> o, col(m16) -> l : coalesced along l
      for (int mt = 0; mt < 2; ++mt)
        for (int r = 0; r < 4; ++r)
          VT[((size_t)(b * DD + ot * 16 + quad * 4 + r)) * LL + lb + mt * 16 +
             m16] = f2h(acc[mt][r]);
    }
  }
}

// ---------------------------------------------------------------------------
// Kernel 2: flash attention, 512 threads = 8 waves = 2 waves/SIMD.
// Wave-groups: grp 0 -> kv [it*128, +64), grp 1 -> kv [it*128+64, +64).
// Private (m,l,O) per group, LDS merge at end.  XOR-swizzled K/V LDS.
// ---------------------------------------------------------------------------
__global__ __launch_bounds__(512, 2) void attn(
    const unsigned short* __restrict__ Qb, const unsigned short* __restrict__ Kb,
    const unsigned short* __restrict__ VT, const int* __restrict__ lens,
    float* __restrict__ out) {
  // [0,65536): Ks (2 grp x 64x256)  [65536,131072): Vs (2 grp x 256x64)
  // [131072,149504): Ps (8 waves x 16x72)
  __shared__ __attribute__((aligned(16))) unsigned char smem[149504];
  const int t = threadIdx.x;
  const int wave = t >> 6, lane = t & 63, quad = lane >> 4, m16 = lane & 15;
  const int grp = wave >> 2, qw = wave & 3, tgl = t & 255;
  unsigned short* Ks = (unsigned short*)(smem + grp * 32768);
  unsigned short* Vs = (unsigned short*)(smem + 65536 + grp * 32768);
  unsigned short* Pw = (unsigned short*)(smem + 131072 + wave * 2304);

  const int b = blockIdx.y;
  const int q0 = blockIdx.x * 64;
  const int len = lens[b];
  const size_t baseQK = (size_t)b * LL * DD;
  const size_t baseVT = (size_t)b * DD * LL;

  half8 qf[8];
  {
    const unsigned short* qrow =
        Qb + baseQK + (size_t)(q0 + qw * 16 + m16) * DD + quad * 8;
    for (int kb = 0; kb < 8; ++kb)
      qf[kb] = __builtin_bit_cast(half8, *(const ushort8*)(qrow + kb * 32));
  }

  floatx4 O[16];
  for (int i = 0; i < 16; ++i) O[i] = (floatx4){0, 0, 0, 0};
  float mrow[4] = {-1e30f, -1e30f, -1e30f, -1e30f};
  float lrow[4] = {0.f, 0.f, 0.f, 0.f};

  ushort8 kreg[8], vreg[8];
  const unsigned short* kbase = Kb + baseQK;
  const unsigned short* vbase = VT + baseVT;

#define LOAD_TILES(KV0)                                                      \
  {                                                                          \
    const unsigned short* kp = kbase + (size_t)(KV0)*DD;                     \
    for (int c = 0; c < 8; ++c)                                              \
      kreg[c] = *(const ushort8*)(kp + (tgl + c * 256) * 8);                 \
    for (int c = 0; c < 8; ++c) {                                            \
      int ch = tgl + c * 256;                                                \
      vreg[c] = *(const ushort8*)(vbase + (size_t)(ch >> 3) * LL + (KV0) +   \
                                  (ch & 7) * 8);                             \
    }                                                                        \
  }

  const int T = (len + 127) >> 7;  // uniform trip count, 128 kv per iter
  LOAD_TILES(grp * 64);

  for (int it = 0; it < T; ++it) {
    const int kv0 = it * 128 + grp * 64;
    __syncthreads();
    for (int c = 0; c < 8; ++c) {
      int ch = tgl + c * 256, row = ch >> 5, cc = ch & 31;
      *(ushort8*)&Ks[row * 256 + (cc ^ (row & 7)) * 8] = kreg[c];
    }
    for (int c = 0; c < 8; ++c) {
      int ch = tgl + c * 256, d = ch >> 3, cc = ch & 7;
      *(ushort8*)&Vs[d * 64 + (cc ^ (d & 7)) * 8] = vreg[c];
    }
    __syncthreads();
    if (it + 1 < T) LOAD_TILES(kv0 + 128);

    if (kv0 < len) {
      // S = Q K^T
      floatx4 s[4];
      for (int n = 0; n < 4; ++n) s[n] = (floatx4){0, 0, 0, 0};
      for (int kb = 0; kb < 8; ++kb)
        for (int n = 0; n < 4; ++n) {
          half8 kf = __builtin_bit_cast(
              half8, *(const ushort8*)&Ks[(n * 16 + m16) * 256 +
                                          (((kb * 4 + quad) ^ (m16 & 7)) * 8)]);
          s[n] = __builtin_amdgcn_mfma_f32_16x16x32_f16(qf[kb], kf, s[n], 0, 0, 0);
        }
      float sv[4][4];
      for (int n = 0; n < 4; ++n) {
        bool valid = (kv0 + n * 16 + m16) < len;
        for (int r = 0; r < 4; ++r)
          sv[n][r] = valid ? s[n][r] * 0.0625f : -1e30f;
      }
      float al[4];
      for (int r = 0; r < 4; ++r) {
        float v = fmaxf(fmaxf(sv[0][r], sv[1][r]), fmaxf(sv[2][r], sv[3][r]));
        v = fmaxf(v, __shfl_xor(v, 1));
        v = fmaxf(v, __shfl_xor(v, 2));
        v = fmaxf(v, __shfl_xor(v, 4));
        v = fmaxf(v, __shfl_xor(v, 8));
        float mn = fmaxf(mrow[r], v);
        al[r] = __expf(mrow[r] - mn);
        mrow[r] = mn;
        float sum = 0.f;
        for (int n = 0; n < 4; ++n) {
          float p = __expf(sv[n][r] - mn);
          Pw[(quad * 4 + r) * 72 + n * 16 + m16] = f2h(p);
          sum += p;
        }
        sum += __shfl_xor(sum, 1);
        sum += __shfl_xor(sum, 2);
        sum += __shfl_xor(sum, 4);
        sum += __shfl_xor(sum, 8);
        lrow[r] = lrow[r] * al[r] + sum;
      }
      for (int i = 0; i < 16; ++i)
        for (int r = 0; r < 4; ++r) O[i][r] *= al[r];
      half8 pf0 = __builtin_bit_cast(half8,
                                     *(const ushort8*)&Pw[m16 * 72 + quad * 8]);
      half8 pf1 = __builtin_bit_cast(
          half8, *(const ushort8*)&Pw[m16 * 72 + 32 + quad * 8]);
      for (int nb = 0; nb < 16; ++nb) {
        half8 vf0 = __builtin_bit_cast(
            half8, *(const ushort8*)&Vs[(nb * 16 + m16) * 64 +
                                        ((quad ^ (m16 & 7)) * 8)]);
        O[nb] = __builtin_amdgcn_mfma_f32_16x16x32_f16(pf0, vf0, O[nb], 0, 0, 0);
        half8 vf1 = __builtin_bit_cast(
            half8, *(const ushort8*)&Vs[(nb * 16 + m16) * 64 +
                                        (((4 + quad) ^ (m16 & 7)) * 8)]);
        O[nb] = __builtin_amdgcn_mfma_f32_16x16x32_f16(pf1, vf1, O[nb], 0, 0, 0);
      }
    }
  }
#undef LOAD_TILES

  // ---- merge group 1 into group 0 via LDS (aliases Ks/Vs region) ----
  __syncthreads();
  float* Om = (float*)(smem) + qw * 4112;       // 16 rows x 257 f32 per wave
  float* ml = (float*)(smem + 65792) + qw * 32; // [2][16] per wave
  if (grp == 1) {
    for (int nb = 0; nb < 16; ++nb)
      for (int r = 0; r < 4; ++r)
        Om[(quad * 4 + r) * 257 + nb * 16 + m16] = O[nb][r];
    if (m16 == 0)
      for (int r = 0; r < 4; ++r) {
        ml[(quad * 4 + r) * 2] = mrow[r];
        ml[(quad * 4 + r) * 2 + 1] = lrow[r];
      }
  }
  __syncthreads();
  if (grp == 0) {
    float a[4], bf[4], inv[4];
    for (int r = 0; r < 4; ++r) {
      float mB = ml[(quad * 4 + r) * 2];
      float lB = ml[(quad * 4 + r) * 2 + 1];
      float m = fmaxf(mrow[r], mB);
      a[r] = __expf(mrow[r] - m);
      bf[r] = __expf(mB - m);
      inv[r] = 1.f / (lrow[r] * a[r] + lB * bf[r]);
    }
    for (int nb = 0; nb < 16; ++nb)
      for (int r = 0; r < 4; ++r) {
        float ob = Om[(quad * 4 + r) * 257 + nb * 16 + m16];
        out[baseQK + (size_t)(q0 + qw * 16 + quad * 4 + r) * DD + nb * 16 +
            m16] = (O[nb][r] * a[r] + ob * bf[r]) * inv[r];
      }
  }
}

extern "C" void kernel_launch(void* const* d_in, const int* in_sizes, int n_in,
                              void* d_out, int out_size, void* d_ws, size_t ws_size,
                              hipStream_t stream) {
  const float* x = (const float*)d_in[0];
  const float* Wq = (const float*)d_in[1];
  const float* Wk = (const float*)d_in[2];
  const float* Wv = (const float*)d_in[3];
  const int* lens = (const int*)d_in[4];
  unsigned short* Qb = (unsigned short*)d_ws;
  unsigned short* Kb = Qb + (size_t)BB * LL * DD;
  unsigned short* VT = Kb + (size_t)BB * LL * DD;
  unsigned short* Wh = VT + (size_t)BB * LL * DD;
  float* out = (float*)d_out;

  wcvt<<<96, 256, 0, stream>>>(Wq, Wk, Wv, Wh);
  proj<<<512, 256, 0, stream>>>(x, Wh, Qb, Kb, VT);
  attn<<<dim3(32, 8), 512, 0, stream>>>(Qb, Kb, VT, lens, out);
}